// Round 8
// baseline (1212.316 us; speedup 1.0000x reference)
//
#include <hip/hip_runtime.h>
#include <hip/hip_bf16.h>
#include <math.h>

#define NDIM 512
#define NB   128
#define NMAT 129
#define EPSF 1e-7f
#define MS  ((size_t)262144)   // matrix stride (floats) = 512*512
#define LTS ((size_t)32768)    // Lt stride per matrix (floats) = 64*512
#define PSTR ((size_t)524288)  // E2 plane stride (floats)

// workspace layout (float offsets). pbG/invG alias E2 (E2 dead after build phase).
#define OFF_E   ((size_t)0)                    // 1,048,576 (E2; later pbG+invG)
#define OFF_PB  ((size_t)0)                    // 129*4096 = 528,384
#define OFF_INV ((size_t)528384)               // 129*64   = 8,256
#define OFF_WM  ((size_t)1048576)              // 262,144
#define OFF_IPR ((size_t)(OFF_WM + 262144))    // 65,536
#define OFF_LPR ((size_t)(OFF_IPR + 65536))    // 128
#define OFF_LD  ((size_t)(OFF_LPR + 128))      // 129 (pad to 1,377,792)
#define OFF_LT  ((size_t)1377792)              // 129*32768 = 4,227,072
#define OFF_MAT ((size_t)(OFF_LT + (size_t)NMAT*LTS))   // ~158 MB total

// ---- in-wave shuffle LU of a 64x64 diagonal block (lane = row) ----
template<int KK>
struct WLU {
  static __device__ __forceinline__ void run(float (&a)[64], int l, float& logp, float& myinv) {
    float piv = __shfl(a[KK], KK, 64);
    float inv = 1.0f / piv;
    logp += logf(fabsf(piv));
    if (l == KK) myinv = inv;
    const float mfac = (l > KK) ? a[KK] * inv : 0.0f;
    if (l > KK) a[KK] = mfac;
    #pragma unroll
    for (int c = KK + 1; c < 64; ++c) {
      float pc = __shfl(a[c], KK, 64);
      a[c] -= mfac * pc;
    }
    WLU<KK + 1>::run(a, l, logp, myinv);
  }
};
template<>
struct WLU<64> {
  static __device__ __forceinline__ void run(float (&)[64], int, float&, float&) {}
};

// ---- L21 row solve against pivot rows in LDS ----
template<int KK>
struct SolveL {
  static __device__ __forceinline__ void run(float (&a)[64], const float* __restrict__ pbs,
                                             const float* __restrict__ invs) {
    const float lkk = a[KK] * invs[KK];
    a[KK] = lkk;
    #pragma unroll
    for (int c = KK + 1; c < 64; ++c)
      a[c] -= lkk * pbs[(KK << 6) + c];    // U row KK (broadcast LDS read)
    SolveL<KK + 1>::run(a, pbs, invs);
  }
};
template<>
struct SolveL<64> {
  static __device__ __forceinline__ void run(float (&)[64], const float*, const float*) {}
};

// ---------- fused prep: Wm (blocks 0..1023), E-IPF (1024..2047), Pr (2048..2175) ----------
__global__ __launch_bounds__(256) void k_prep(const float* __restrict__ Vc, const float* __restrict__ W,
                                              const float* __restrict__ Ec, const int* __restrict__ x,
                                              float* __restrict__ Wm, float* __restrict__ E2,
                                              float* __restrict__ invPr, float* __restrict__ logPr) {
  const int blk = blockIdx.x;
  if (blk < 1024) {
    int idx = blk*256 + threadIdx.x;
    int i = idx >> 9, j = idx & 511;
    float v = 0.f;
    if (i > j)      v = 1.f / (1.f + expf(-W[i*NDIM + j]));
    else if (i < j) v = 1.f / (1.f + expf(-W[j*NDIM + i]));
    Wm[idx] = v;
  } else if (blk < 2048) {
    int idx = (blk-1024)*256 + threadIdx.x;   // i*512 + j
    int i = idx >> 9, j = idx & 511;
    float4 ec = reinterpret_cast<const float4*>(Ec)[idx];
    float e00 = expf(ec.x), e01 = expf(ec.y), e10 = expf(ec.z), e11 = expf(ec.w);
    float s = e00 + e01 + e10 + e11;
    float inv = 1.f / s;
    e00 *= inv; e01 *= inv; e10 *= inv; e11 *= inv;
    float vi0 = Vc[2*i], vi1 = Vc[2*i+1];
    float mi = fmaxf(vi0, vi1);
    float ei0 = expf(vi0 - mi), ei1 = expf(vi1 - mi);
    float A0 = ei0/(ei0+ei1), A1 = ei1/(ei0+ei1);
    float vj0 = Vc[2*j], vj1 = Vc[2*j+1];
    float mj = fmaxf(vj0, vj1);
    float ej0 = expf(vj0 - mj), ej1 = expf(vj1 - mj);
    float B0 = ej0/(ej0+ej1), B1 = ej1/(ej0+ej1);
    for (int t = 0; t < 10; ++t) {
      float rm0 = e00 + e01 + EPSF, rm1 = e10 + e11 + EPSF;
      float cm0 = e00 + e10 + EPSF, cm1 = e01 + e11 + EPSF;
      float f0 = A0 / rm0, f1 = A1 / rm1;
      e00 *= f0; e01 *= f0; e10 *= f1; e11 *= f1;
      float g0 = B0 / cm0, g1 = B1 / cm1;
      e00 *= g0; e10 *= g0; e01 *= g1; e11 *= g1;
      float ss = e00 + e01 + e10 + e11 + EPSF;
      float iv = 1.f / ss;
      e00 *= iv; e01 *= iv; e10 *= iv; e11 *= iv;
    }
    if (i == j) { e00 = 0.f; e01 = 0.f; e10 = 0.f; e11 = 0.f; }
    e00 = fminf(fmaxf(e00, 0.f), 1.f);
    e01 = fminf(fmaxf(e01, 0.f), 1.f);
    e10 = fminf(fmaxf(e10, 0.f), 1.f);
    e11 = fminf(fmaxf(e11, 0.f), 1.f);
    reinterpret_cast<float2*>(E2)[idx]        = make_float2(e00, e01);
    reinterpret_cast<float2*>(E2 + PSTR)[idx] = make_float2(e10, e11);
  } else {
    const int b = blk - 2048;
    const int tid = threadIdx.x;
    float acc = 0.f;
    for (int ii = tid; ii < NDIM; ii += 256) {
      const int xv = x[b*NDIM + ii];
      float v0 = Vc[2*ii], v1 = Vc[2*ii+1];
      float mx = fmaxf(v0, v1);
      float e0 = expf(v0 - mx), e1 = expf(v1 - mx);
      float p = (xv ? e1 : e0) / (e0 + e1);
      invPr[b*NDIM + ii] = 1.f / p;
      acc += logf(p);
    }
    for (int off = 32; off > 0; off >>= 1) acc += __shfl_down(acc, off, 64);
    __shared__ float sw[4];
    if ((tid & 63) == 0) sw[tid >> 6] = acc;
    __syncthreads();
    if (tid == 0) logPr[b] = sw[0] + sw[1] + sw[2] + sw[3];
  }
}

// ---------- build 511x511 minors: one wave per row, 8 elems/lane ----------
__global__ __launch_bounds__(512) void k_build(const int* __restrict__ x, const float* __restrict__ E2,
                                               const float* __restrict__ Wm, const float* __restrict__ invPr,
                                               float* __restrict__ Mall) {
  const int b = blockIdx.x;            // fast -> L2 locality on E2/Wm rows
  const int tid = threadIdx.x;
  const int w = tid >> 6;
  const int l = tid & 63;
  const int i = blockIdx.y*8 + w;      // 0..511 ; i==0 -> writes pad row 511
  const int j0 = 8*l;
  if (i == 0) {
    float* Mrow = Mall + (size_t)b*MS + (size_t)511*NDIM;
    #pragma unroll
    for (int k = 0; k < 8; ++k) Mrow[j0+k] = (j0+k == 511) ? 1.f : 0.f;
    return;
  }
  float* Mrow = Mall + (size_t)b*MS + (size_t)(i-1)*NDIM;
  float4 wma = *(const float4*)(Wm + i*NDIM + j0);
  float4 wmb = *(const float4*)(Wm + i*NDIM + j0 + 4);
  float wp[8];
  if (b < NB) {
    const int xi = x[b*NDIM + i];
    const float ipi = invPr[b*NDIM + i];
    int4 xja = *(const int4*)(x + b*NDIM + j0);
    int4 xjb = *(const int4*)(x + b*NDIM + j0 + 4);
    float4 ipa = *(const float4*)(invPr + b*NDIM + j0);
    float4 ipb = *(const float4*)(invPr + b*NDIM + j0 + 4);
    const float* pe = E2 + (size_t)xi*PSTR + ((size_t)i << 10) + 16*l;
    float4 e0 = *(const float4*)(pe);
    float4 e1 = *(const float4*)(pe + 4);
    float4 e2 = *(const float4*)(pe + 8);
    float4 e3 = *(const float4*)(pe + 12);
    float ev[8];
    ev[0] = xja.x ? e0.y : e0.x;
    ev[1] = xja.y ? e0.w : e0.z;
    ev[2] = xja.z ? e1.y : e1.x;
    ev[3] = xja.w ? e1.w : e1.z;
    ev[4] = xjb.x ? e2.y : e2.x;
    ev[5] = xjb.y ? e2.w : e2.z;
    ev[6] = xjb.z ? e3.y : e3.x;
    ev[7] = xjb.w ? e3.w : e3.z;
    float ip[8] = {ipa.x,ipa.y,ipa.z,ipa.w,ipb.x,ipb.y,ipb.z,ipb.w};
    float wm[8] = {wma.x,wma.y,wma.z,wma.w,wmb.x,wmb.y,wmb.z,wmb.w};
    #pragma unroll
    for (int k = 0; k < 8; ++k) wp[k] = wm[k]*ev[k]*ipi*ip[k];
  } else {
    wp[0]=wma.x; wp[1]=wma.y; wp[2]=wma.z; wp[3]=wma.w;
    wp[4]=wmb.x; wp[5]=wmb.y; wp[6]=wmb.z; wp[7]=wmb.w;
  }
  float rs = wp[0]+wp[1]+wp[2]+wp[3]+wp[4]+wp[5]+wp[6]+wp[7];
  #pragma unroll
  for (int m = 1; m < 64; m <<= 1) rs += __shfl_xor(rs, m, 64);
  #pragma unroll
  for (int k = 0; k < 8; ++k) {
    const int j = j0 + k;
    float val = (j == i) ? rs : -wp[k];
    int col = j - 1;
    if (j == 0) { col = 511; val = 0.f; }
    Mrow[col] = val;
  }
}

// ---------- step-0 diagonal LU: one wave per matrix ----------
__global__ __launch_bounds__(64) void k_wlu0(const float* __restrict__ Mall, float* __restrict__ pbG,
                                             float* __restrict__ invG, float* __restrict__ Ld) {
  const int b = blockIdx.x;
  const int l = threadIdx.x;
  const float* rowp = Mall + (size_t)b*MS + (size_t)l*NDIM;
  float a[64];
  #pragma unroll
  for (int c4 = 0; c4 < 16; ++c4) {
    float4 v = *(const float4*)(rowp + c4*4);
    a[c4*4+0]=v.x; a[c4*4+1]=v.y; a[c4*4+2]=v.z; a[c4*4+3]=v.w;
  }
  float logp = 0.f, myinv = 0.f;
  WLU<0>::run(a, l, logp, myinv);
  float* pbr = pbG + ((size_t)b << 12) + (l << 6);
  #pragma unroll
  for (int c4 = 0; c4 < 16; ++c4)
    *(float4*)(pbr + c4*4) = make_float4(a[c4*4], a[c4*4+1], a[c4*4+2], a[c4*4+3]);
  invG[(b << 6) + l] = myinv;
  if (l == 0) Ld[b] = logp;
}

// ---------- merged L21-solve (items 0..mrem) + U12-TRSM (items mrem..2mrem) ----------
__global__ __launch_bounds__(256) void k_solve(float* __restrict__ Mall, float* __restrict__ Lt,
                                               const float* __restrict__ pbG, const float* __restrict__ invG,
                                               int k0, int mrem) {
  const int b = blockIdx.x;
  __shared__ float pbs[4096];
  __shared__ float invs[64];
  const int tid = threadIdx.x;
  {
    const float4* src = (const float4*)(pbG + ((size_t)b << 12));
    #pragma unroll
    for (int i = 0; i < 4; ++i)
      ((float4*)pbs)[tid + 256*i] = src[tid + 256*i];
    if (tid < 64) invs[tid] = invG[(b << 6) + tid];
  }
  __syncthreads();
  const int it = blockIdx.y*256 + tid;
  if (it >= 2*mrem) return;
  float* M = Mall + (size_t)b*MS;
  if (it < mrem) {
    // L21 row solve -> Lt
    const int r = it;
    float a[64];
    const float* rowp = M + (size_t)(k0+64+r)*NDIM + k0;
    #pragma unroll
    for (int c4 = 0; c4 < 16; ++c4) {
      float4 v = *(const float4*)(rowp + c4*4);
      a[c4*4+0]=v.x; a[c4*4+1]=v.y; a[c4*4+2]=v.z; a[c4*4+3]=v.w;
    }
    SolveL<0>::run(a, pbs, invs);
    float* L = Lt + (size_t)b*LTS;
    #pragma unroll
    for (int c = 0; c < 64; ++c) L[(size_t)c*NDIM + 64 + r] = a[c];
  } else {
    // U12 column solve in place
    const int col = k0 + 64 + (it - mrem);
    float u[64];
    #pragma unroll
    for (int rr = 0; rr < 64; ++rr) u[rr] = M[(size_t)(k0+rr)*NDIM + col];
    #pragma unroll
    for (int p = 0; p < 63; ++p) {
      const float lv = u[p];
      #pragma unroll
      for (int kk = p+1; kk < 64; ++kk)
        u[kk] -= pbs[(kk << 6) + p] * lv;     // L11[kk][p]
    }
    #pragma unroll
    for (int rr = 1; rr < 64; ++rr) M[(size_t)(k0+rr)*NDIM + col] = u[rr];
  }
}

// ---------- trailing update + merged next-step diagonal LU in block (b,0,0) ----------
__global__ __launch_bounds__(256, 2) void k_gemm(float* __restrict__ Mall, const float* __restrict__ Lt,
                                                 float* __restrict__ pbG, float* __restrict__ invG,
                                                 float* __restrict__ Ld, int k0) {
  const int b = blockIdx.x;
  float* __restrict__ M = Mall + (size_t)b*MS;
  const float* __restrict__ L = Lt + (size_t)b*LTS;
  __shared__ float As[64][68];     // As[p][r] = L21[r][p]
  __shared__ float Bs[64][68];     // Bs[p][c] = U12[p][c]
  const int tid = threadIdx.x;
  const int tx = tid & 15, ty = tid >> 4;
  const int rowbase = 64 + blockIdx.y*64;
  const int colbase = 64 + blockIdx.z*64;
  #pragma unroll
  for (int i = 0; i < 4; ++i) {
    int q = tid + 256*i;
    int p = q >> 4, f = q & 15;
    *(float4*)&As[p][f*4] = *(const float4*)&L[(size_t)p*NDIM + rowbase + f*4];
    *(float4*)&Bs[p][f*4] = *(const float4*)&M[(size_t)(k0+p)*NDIM + (k0+colbase) + f*4];
  }
  float* Crow = M + (size_t)(k0+rowbase+ty*4)*NDIM + (k0+colbase+tx*4);
  float4 c0 = *(float4*)(Crow + 0*NDIM);
  float4 c1 = *(float4*)(Crow + 1*NDIM);
  float4 c2 = *(float4*)(Crow + 2*NDIM);
  float4 c3 = *(float4*)(Crow + 3*NDIM);
  __syncthreads();
  #pragma unroll
  for (int p = 0; p < 64; ++p) {
    const float4 av = *(const float4*)&As[p][ty*4];
    const float4 bv = *(const float4*)&Bs[p][tx*4];
    c0.x -= av.x*bv.x; c0.y -= av.x*bv.y; c0.z -= av.x*bv.z; c0.w -= av.x*bv.w;
    c1.x -= av.y*bv.x; c1.y -= av.y*bv.y; c1.z -= av.y*bv.z; c1.w -= av.y*bv.w;
    c2.x -= av.z*bv.x; c2.y -= av.z*bv.y; c2.z -= av.z*bv.z; c2.w -= av.z*bv.w;
    c3.x -= av.w*bv.x; c3.y -= av.w*bv.y; c3.z -= av.w*bv.z; c3.w -= av.w*bv.w;
  }
  *(float4*)(Crow + 0*NDIM) = c0;
  *(float4*)(Crow + 1*NDIM) = c1;
  *(float4*)(Crow + 2*NDIM) = c2;
  *(float4*)(Crow + 3*NDIM) = c3;

  // merged diagonal LU for the NEXT step: block (b,0,0) holds the new diagonal tile
  if (blockIdx.y == 0 && blockIdx.z == 0) {
    __syncthreads();
    *(float4*)&As[ty*4+0][tx*4] = c0;
    *(float4*)&As[ty*4+1][tx*4] = c1;
    *(float4*)&As[ty*4+2][tx*4] = c2;
    *(float4*)&As[ty*4+3][tx*4] = c3;
    __syncthreads();
    if (tid < 64) {
      float a[64];
      #pragma unroll
      for (int c4 = 0; c4 < 16; ++c4) {
        float4 v = *(const float4*)&As[tid][c4*4];
        a[c4*4+0]=v.x; a[c4*4+1]=v.y; a[c4*4+2]=v.z; a[c4*4+3]=v.w;
      }
      float logp = 0.f, myinv = 0.f;
      WLU<0>::run(a, tid, logp, myinv);
      float* pbr = pbG + ((size_t)b << 12) + (tid << 6);
      #pragma unroll
      for (int c4 = 0; c4 < 16; ++c4)
        *(float4*)(pbr + c4*4) = make_float4(a[c4*4], a[c4*4+1], a[c4*4+2], a[c4*4+3]);
      invG[(b << 6) + tid] = myinv;
      if (tid == 0) Ld[b] += logp;
    }
  }
}

// ---------- final combine ----------
__global__ void k_final(const float* __restrict__ logPr, const float* __restrict__ logdets,
                        float* __restrict__ out) {
  int t = threadIdx.x;
  if (t < NB) out[t] = logPr[t] + logdets[t] - logdets[NB];
}

extern "C" void kernel_launch(void* const* d_in, const int* in_sizes, int n_in,
                              void* d_out, int out_size, void* d_ws, size_t ws_size,
                              hipStream_t stream) {
  const int*   x  = (const int*)  d_in[0];
  const float* W  = (const float*)d_in[1];
  const float* Vc = (const float*)d_in[2];
  const float* Ec = (const float*)d_in[3];
  float* out = (float*)d_out;
  float* ws  = (float*)d_ws;
  (void)in_sizes; (void)n_in; (void)out_size; (void)ws_size;  // needs ~158 MiB of ws

  float* Mat  = ws + OFF_MAT;
  float* Lt   = ws + OFF_LT;
  float* Ld   = ws + OFF_LD;
  float* pbg  = ws + OFF_PB;    // aliases E2 (dead after build)
  float* invg = ws + OFF_INV;   // aliases E2

  k_prep<<<2176, 256, 0, stream>>>(Vc, W, Ec, x, ws + OFF_WM, ws + OFF_E,
                                   ws + OFF_IPR, ws + OFF_LPR);
  dim3 gb(NMAT, 64);
  k_build<<<gb, 512, 0, stream>>>(x, ws + OFF_E, ws + OFF_WM, ws + OFF_IPR, Mat);
  k_wlu0<<<NMAT, 64, 0, stream>>>(Mat, pbg, invg, Ld);

  for (int s = 0; s < 7; ++s) {
    const int k0 = s*64;
    const int mrem = NDIM - k0 - 64;
    dim3 gs(NMAT, (2*mrem + 255)/256);
    k_solve<<<gs, 256, 0, stream>>>(Mat, Lt, pbg, invg, k0, mrem);
    const int nt = mrem/64;
    dim3 gg(NMAT, nt, nt);
    k_gemm<<<gg, 256, 0, stream>>>(Mat, Lt, pbg, invg, Ld, k0);
  }
  k_final<<<1, 128, 0, stream>>>(ws + OFF_LPR, Ld, out);
}

// Round 9
// 779.887 us; speedup vs baseline: 1.5545x; 1.5545x over previous
//
#include <hip/hip_runtime.h>
#include <hip/hip_bf16.h>
#include <math.h>

#define NDIM 512
#define NB   128
#define NMAT 129
#define EPSF 1e-7f
#define MS  ((size_t)262144)   // matrix stride (floats) = 512*512
#define LTS ((size_t)32768)    // Lt stride per matrix (floats) = 64*512
#define PSTR ((size_t)524288)  // E2 plane stride (floats)

// workspace layout (float offsets). InvT aliases E2 (E2 dead after build phase).
#define OFF_E   ((size_t)0)                    // 1,048,576 (E2; later InvT)
#define OFF_PB  ((size_t)0)                    // 129*4096 = 528,384 (InvT)
#define OFF_WM  ((size_t)1048576)              // 262,144
#define OFF_IPR ((size_t)(OFF_WM + 262144))    // 65,536
#define OFF_LPR ((size_t)(OFF_IPR + 65536))    // 128
#define OFF_LD  ((size_t)(OFF_LPR + 128))      // 129 (pad to 1,377,792)
#define OFF_LT  ((size_t)1377792)              // 129*32768 = 4,227,072
#define OFF_MAT ((size_t)(OFF_LT + (size_t)NMAT*LTS))   // ~158 MB total

// ---- in-wave shuffle LU of a 64x64 diagonal block (lane = row) ----
template<int KK>
struct WLU {
  static __device__ __forceinline__ void run(float (&a)[64], int l, float& logp, float& myinv) {
    float piv = __shfl(a[KK], KK, 64);
    float inv = 1.0f / piv;
    logp += logf(fabsf(piv));
    if (l == KK) myinv = inv;
    const float mfac = (l > KK) ? a[KK] * inv : 0.0f;
    if (l > KK) a[KK] = mfac;
    #pragma unroll
    for (int c = KK + 1; c < 64; ++c) {
      float pc = __shfl(a[c], KK, 64);
      a[c] -= mfac * pc;
    }
    WLU<KK + 1>::run(a, l, logp, myinv);
  }
};
template<>
struct WLU<64> {
  static __device__ __forceinline__ void run(float (&)[64], int, float&, float&) {}
};

// ---- forward solve L*y = e_j (unit lower; L multipliers in pbs[r][k], k<r) ----
template<int R>
struct Fwd {
  static __device__ __forceinline__ void run(float (&y)[64], const float (*pbs)[68], int j) {
    float acc = (R == j) ? 1.f : 0.f;
    #pragma unroll
    for (int k = 0; k < R; ++k) acc -= pbs[R][k] * y[k];
    y[R] = acc;
    Fwd<R + 1>::run(y, pbs, j);
  }
};
template<>
struct Fwd<64> {
  static __device__ __forceinline__ void run(float (&)[64], const float (*)[68], int) {}
};

// ---- backward solve U*x = y in place (U entries pbs[r][k], k>=r; 1/U[r][r] in invs) ----
template<int R>
struct Bwd {
  static __device__ __forceinline__ void run(float (&y)[64], const float (*pbs)[68],
                                             const float* invs) {
    float acc = y[R];
    #pragma unroll
    for (int k = R + 1; k < 64; ++k) acc -= pbs[R][k] * y[k];
    y[R] = acc * invs[R];
    Bwd<R - 1>::run(y, pbs, invs);
  }
};
template<>
struct Bwd<-1> {
  static __device__ __forceinline__ void run(float (&)[64], const float (*)[68], const float*) {}
};

// ---------- fused prep: Wm (blocks 0..1023), E-IPF (1024..2047), Pr (2048..2175) ----------
__global__ __launch_bounds__(256) void k_prep(const float* __restrict__ Vc, const float* __restrict__ W,
                                              const float* __restrict__ Ec, const int* __restrict__ x,
                                              float* __restrict__ Wm, float* __restrict__ E2,
                                              float* __restrict__ invPr, float* __restrict__ logPr) {
  const int blk = blockIdx.x;
  if (blk < 1024) {
    int idx = blk*256 + threadIdx.x;
    int i = idx >> 9, j = idx & 511;
    float v = 0.f;
    if (i > j)      v = 1.f / (1.f + expf(-W[i*NDIM + j]));
    else if (i < j) v = 1.f / (1.f + expf(-W[j*NDIM + i]));
    Wm[idx] = v;
  } else if (blk < 2048) {
    int idx = (blk-1024)*256 + threadIdx.x;   // i*512 + j
    int i = idx >> 9, j = idx & 511;
    float4 ec = reinterpret_cast<const float4*>(Ec)[idx];
    float e00 = expf(ec.x), e01 = expf(ec.y), e10 = expf(ec.z), e11 = expf(ec.w);
    float s = e00 + e01 + e10 + e11;
    float inv = 1.f / s;
    e00 *= inv; e01 *= inv; e10 *= inv; e11 *= inv;
    float vi0 = Vc[2*i], vi1 = Vc[2*i+1];
    float mi = fmaxf(vi0, vi1);
    float ei0 = expf(vi0 - mi), ei1 = expf(vi1 - mi);
    float A0 = ei0/(ei0+ei1), A1 = ei1/(ei0+ei1);
    float vj0 = Vc[2*j], vj1 = Vc[2*j+1];
    float mj = fmaxf(vj0, vj1);
    float ej0 = expf(vj0 - mj), ej1 = expf(vj1 - mj);
    float B0 = ej0/(ej0+ej1), B1 = ej1/(ej0+ej1);
    for (int t = 0; t < 10; ++t) {
      float rm0 = e00 + e01 + EPSF, rm1 = e10 + e11 + EPSF;
      float cm0 = e00 + e10 + EPSF, cm1 = e01 + e11 + EPSF;
      float f0 = A0 / rm0, f1 = A1 / rm1;
      e00 *= f0; e01 *= f0; e10 *= f1; e11 *= f1;
      float g0 = B0 / cm0, g1 = B1 / cm1;
      e00 *= g0; e10 *= g0; e01 *= g1; e11 *= g1;
      float ss = e00 + e01 + e10 + e11 + EPSF;
      float iv = 1.f / ss;
      e00 *= iv; e01 *= iv; e10 *= iv; e11 *= iv;
    }
    if (i == j) { e00 = 0.f; e01 = 0.f; e10 = 0.f; e11 = 0.f; }
    e00 = fminf(fmaxf(e00, 0.f), 1.f);
    e01 = fminf(fmaxf(e01, 0.f), 1.f);
    e10 = fminf(fmaxf(e10, 0.f), 1.f);
    e11 = fminf(fmaxf(e11, 0.f), 1.f);
    reinterpret_cast<float2*>(E2)[idx]        = make_float2(e00, e01);
    reinterpret_cast<float2*>(E2 + PSTR)[idx] = make_float2(e10, e11);
  } else {
    const int b = blk - 2048;
    const int tid = threadIdx.x;
    float acc = 0.f;
    for (int ii = tid; ii < NDIM; ii += 256) {
      const int xv = x[b*NDIM + ii];
      float v0 = Vc[2*ii], v1 = Vc[2*ii+1];
      float mx = fmaxf(v0, v1);
      float e0 = expf(v0 - mx), e1 = expf(v1 - mx);
      float p = (xv ? e1 : e0) / (e0 + e1);
      invPr[b*NDIM + ii] = 1.f / p;
      acc += logf(p);
    }
    for (int off = 32; off > 0; off >>= 1) acc += __shfl_down(acc, off, 64);
    __shared__ float sw[4];
    if ((tid & 63) == 0) sw[tid >> 6] = acc;
    __syncthreads();
    if (tid == 0) logPr[b] = sw[0] + sw[1] + sw[2] + sw[3];
  }
}

// ---------- build 511x511 minors: one wave per row, 8 elems/lane ----------
__global__ __launch_bounds__(512) void k_build(const int* __restrict__ x, const float* __restrict__ E2,
                                               const float* __restrict__ Wm, const float* __restrict__ invPr,
                                               float* __restrict__ Mall) {
  const int b = blockIdx.x;
  const int tid = threadIdx.x;
  const int w = tid >> 6;
  const int l = tid & 63;
  const int i = blockIdx.y*8 + w;      // 0..511 ; i==0 -> writes pad row 511
  const int j0 = 8*l;
  if (i == 0) {
    float* Mrow = Mall + (size_t)b*MS + (size_t)511*NDIM;
    #pragma unroll
    for (int k = 0; k < 8; ++k) Mrow[j0+k] = (j0+k == 511) ? 1.f : 0.f;
    return;
  }
  float* Mrow = Mall + (size_t)b*MS + (size_t)(i-1)*NDIM;
  float4 wma = *(const float4*)(Wm + i*NDIM + j0);
  float4 wmb = *(const float4*)(Wm + i*NDIM + j0 + 4);
  float wp[8];
  if (b < NB) {
    const int xi = x[b*NDIM + i];
    const float ipi = invPr[b*NDIM + i];
    int4 xja = *(const int4*)(x + b*NDIM + j0);
    int4 xjb = *(const int4*)(x + b*NDIM + j0 + 4);
    float4 ipa = *(const float4*)(invPr + b*NDIM + j0);
    float4 ipb = *(const float4*)(invPr + b*NDIM + j0 + 4);
    const float* pe = E2 + (size_t)xi*PSTR + ((size_t)i << 10) + 16*l;
    float4 e0 = *(const float4*)(pe);
    float4 e1 = *(const float4*)(pe + 4);
    float4 e2 = *(const float4*)(pe + 8);
    float4 e3 = *(const float4*)(pe + 12);
    float ev[8];
    ev[0] = xja.x ? e0.y : e0.x;
    ev[1] = xja.y ? e0.w : e0.z;
    ev[2] = xja.z ? e1.y : e1.x;
    ev[3] = xja.w ? e1.w : e1.z;
    ev[4] = xjb.x ? e2.y : e2.x;
    ev[5] = xjb.y ? e2.w : e2.z;
    ev[6] = xjb.z ? e3.y : e3.x;
    ev[7] = xjb.w ? e3.w : e3.z;
    float ip[8] = {ipa.x,ipa.y,ipa.z,ipa.w,ipb.x,ipb.y,ipb.z,ipb.w};
    float wm[8] = {wma.x,wma.y,wma.z,wma.w,wmb.x,wmb.y,wmb.z,wmb.w};
    #pragma unroll
    for (int k = 0; k < 8; ++k) wp[k] = wm[k]*ev[k]*ipi*ip[k];
  } else {
    wp[0]=wma.x; wp[1]=wma.y; wp[2]=wma.z; wp[3]=wma.w;
    wp[4]=wmb.x; wp[5]=wmb.y; wp[6]=wmb.z; wp[7]=wmb.w;
  }
  float rs = wp[0]+wp[1]+wp[2]+wp[3]+wp[4]+wp[5]+wp[6]+wp[7];
  #pragma unroll
  for (int m = 1; m < 64; m <<= 1) rs += __shfl_xor(rs, m, 64);
  #pragma unroll
  for (int k = 0; k < 8; ++k) {
    const int j = j0 + k;
    float val = (j == i) ? rs : -wp[k];
    int col = j - 1;
    if (j == 0) { col = 511; val = 0.f; }
    Mrow[col] = val;
  }
}

// ---------- per-step: WLU of A11 (logdet) + explicit A11^{-1} (stored transposed) ----------
__global__ __launch_bounds__(64) void k_inv(const float* __restrict__ Mall, float* __restrict__ InvT,
                                            float* __restrict__ Ld, int k0, int mrem) {
  const int b = blockIdx.x;
  const int l = threadIdx.x;
  __shared__ float pbs[64][68];
  __shared__ float invs[64];
  const float* rowp = Mall + (size_t)b*MS + (size_t)(k0+l)*NDIM + k0;
  float a[64];
  #pragma unroll
  for (int c4 = 0; c4 < 16; ++c4) {
    float4 v = *(const float4*)(rowp + c4*4);
    a[c4*4+0]=v.x; a[c4*4+1]=v.y; a[c4*4+2]=v.z; a[c4*4+3]=v.w;
  }
  float logp = 0.f, myinv = 0.f;
  WLU<0>::run(a, l, logp, myinv);
  #pragma unroll
  for (int c4 = 0; c4 < 16; ++c4)
    *(float4*)&pbs[l][c4*4] = make_float4(a[c4*4], a[c4*4+1], a[c4*4+2], a[c4*4+3]);
  invs[l] = myinv;
  if (l == 0) Ld[b] = (k0 == 0) ? logp : (Ld[b] + logp);
  __syncthreads();
  if (mrem > 0) {
    // thread l computes column l of A11^{-1}: solve L*y = e_l, then U*x = y.
    float y[64];
    Fwd<0>::run(y, pbs, l);
    Bwd<63>::run(y, pbs, invs);
    float* outp = InvT + ((size_t)b << 12) + (l << 6);   // InvT[b][col l][row r]
    #pragma unroll
    for (int c4 = 0; c4 < 16; ++c4)
      *(float4*)(outp + c4*4) = make_float4(y[c4*4], y[c4*4+1], y[c4*4+2], y[c4*4+3]);
  }
}

// ---------- T1 = A21 * A11inv, written transposed to Lt (gemm As layout) ----------
__global__ __launch_bounds__(256, 4) void k_tr1(const float* __restrict__ Mall,
                                                const float* __restrict__ InvT,
                                                float* __restrict__ Lt, int k0) {
  const int b = blockIdx.x;
  const int ry = blockIdx.y;
  const float* __restrict__ M = Mall + (size_t)b*MS;
  __shared__ float As[64][68];     // As[p][r] = A21[r][p]
  __shared__ float Bs[64][68];     // Bs[p][c] = Inv[p][c]
  const int tid = threadIdx.x;
  // stage A21 tile (rows k0+64+ry*64 .. +63, cols k0..k0+63), transposed into As
  #pragma unroll
  for (int i = 0; i < 4; ++i) {
    int q = tid + 256*i;
    int r = q >> 4, p4 = (q & 15)*4;
    float4 v = *(const float4*)&M[(size_t)(k0+64+ry*64+r)*NDIM + k0 + p4];
    As[p4+0][r]=v.x; As[p4+1][r]=v.y; As[p4+2][r]=v.z; As[p4+3][r]=v.w;
  }
  // stage InvT (col-major inverse) transposed into Bs: Bs[p][c] = InvT[c][p]
  const float* invt = InvT + ((size_t)b << 12);
  #pragma unroll
  for (int i = 0; i < 4; ++i) {
    int q = tid + 256*i;
    int f0 = q*4;
    int c = f0 >> 6, p0 = f0 & 63;
    float4 v = *(const float4*)(invt + f0);
    Bs[p0+0][c]=v.x; Bs[p0+1][c]=v.y; Bs[p0+2][c]=v.z; Bs[p0+3][c]=v.w;
  }
  __syncthreads();
  const int tx = tid & 15, ty = tid >> 4;   // tx -> rows, ty -> cols
  float acc[4][4];
  #pragma unroll
  for (int r = 0; r < 4; ++r)
    #pragma unroll
    for (int c = 0; c < 4; ++c) acc[r][c] = 0.f;
  #pragma unroll
  for (int p = 0; p < 64; ++p) {
    const float4 av = *(const float4*)&As[p][tx*4];
    const float4 bv = *(const float4*)&Bs[p][ty*4];
    acc[0][0] += av.x*bv.x; acc[0][1] += av.x*bv.y; acc[0][2] += av.x*bv.z; acc[0][3] += av.x*bv.w;
    acc[1][0] += av.y*bv.x; acc[1][1] += av.y*bv.y; acc[1][2] += av.y*bv.z; acc[1][3] += av.y*bv.w;
    acc[2][0] += av.z*bv.x; acc[2][1] += av.z*bv.y; acc[2][2] += av.z*bv.z; acc[2][3] += av.z*bv.w;
    acc[3][0] += av.w*bv.x; acc[3][1] += av.w*bv.y; acc[3][2] += av.w*bv.z; acc[3][3] += av.w*bv.w;
  }
  // write transposed: Lt[c][panel_row], panel_row = 64+ry*64+tx*4+r  (coalesced over tx)
  float* L = Lt + (size_t)b*LTS;
  #pragma unroll
  for (int c = 0; c < 4; ++c)
    *(float4*)&L[(size_t)(ty*4+c)*NDIM + 64 + ry*64 + tx*4] =
        make_float4(acc[0][c], acc[1][c], acc[2][c], acc[3][c]);
}

// ---------- trailing update: C -= T1 * A12, 64x64 tile, 4x4/thread (round-6-exact) ----------
__global__ __launch_bounds__(256, 4) void k_gemm(float* __restrict__ Mall, const float* __restrict__ Lt,
                                                 int k0) {
  const int b = blockIdx.x;
  float* __restrict__ M = Mall + (size_t)b*MS;
  const float* __restrict__ L = Lt + (size_t)b*LTS;
  __shared__ float As[64][68];     // As[p][r] = T1[r][p]
  __shared__ float Bs[64][68];     // Bs[p][c] = A12[p][c]
  const int tid = threadIdx.x;
  const int tx = tid & 15, ty = tid >> 4;
  const int rowbase = 64 + blockIdx.y*64;
  const int colbase = 64 + blockIdx.z*64;
  #pragma unroll
  for (int i = 0; i < 4; ++i) {
    int q = tid + 256*i;
    int p = q >> 4, f = q & 15;
    *(float4*)&As[p][f*4] = *(const float4*)&L[(size_t)p*NDIM + rowbase + f*4];
    *(float4*)&Bs[p][f*4] = *(const float4*)&M[(size_t)(k0+p)*NDIM + (k0+colbase) + f*4];
  }
  float* Crow = M + (size_t)(k0+rowbase+ty*4)*NDIM + (k0+colbase+tx*4);
  float4 c0 = *(float4*)(Crow + 0*NDIM);
  float4 c1 = *(float4*)(Crow + 1*NDIM);
  float4 c2 = *(float4*)(Crow + 2*NDIM);
  float4 c3 = *(float4*)(Crow + 3*NDIM);
  __syncthreads();
  #pragma unroll
  for (int p = 0; p < 64; ++p) {
    const float4 av = *(const float4*)&As[p][ty*4];
    const float4 bv = *(const float4*)&Bs[p][tx*4];
    c0.x -= av.x*bv.x; c0.y -= av.x*bv.y; c0.z -= av.x*bv.z; c0.w -= av.x*bv.w;
    c1.x -= av.y*bv.x; c1.y -= av.y*bv.y; c1.z -= av.y*bv.z; c1.w -= av.y*bv.w;
    c2.x -= av.z*bv.x; c2.y -= av.z*bv.y; c2.z -= av.z*bv.z; c2.w -= av.z*bv.w;
    c3.x -= av.w*bv.x; c3.y -= av.w*bv.y; c3.z -= av.w*bv.z; c3.w -= av.w*bv.w;
  }
  *(float4*)(Crow + 0*NDIM) = c0;
  *(float4*)(Crow + 1*NDIM) = c1;
  *(float4*)(Crow + 2*NDIM) = c2;
  *(float4*)(Crow + 3*NDIM) = c3;
}

// ---------- final combine ----------
__global__ void k_final(const float* __restrict__ logPr, const float* __restrict__ logdets,
                        float* __restrict__ out) {
  int t = threadIdx.x;
  if (t < NB) out[t] = logPr[t] + logdets[t] - logdets[NB];
}

extern "C" void kernel_launch(void* const* d_in, const int* in_sizes, int n_in,
                              void* d_out, int out_size, void* d_ws, size_t ws_size,
                              hipStream_t stream) {
  const int*   x  = (const int*)  d_in[0];
  const float* W  = (const float*)d_in[1];
  const float* Vc = (const float*)d_in[2];
  const float* Ec = (const float*)d_in[3];
  float* out = (float*)d_out;
  float* ws  = (float*)d_ws;
  (void)in_sizes; (void)n_in; (void)out_size; (void)ws_size;  // needs ~158 MiB of ws

  float* Mat  = ws + OFF_MAT;
  float* Lt   = ws + OFF_LT;
  float* Ld   = ws + OFF_LD;
  float* invt = ws + OFF_PB;    // aliases E2 (dead after build)

  k_prep<<<2176, 256, 0, stream>>>(Vc, W, Ec, x, ws + OFF_WM, ws + OFF_E,
                                   ws + OFF_IPR, ws + OFF_LPR);
  dim3 gb(NMAT, 64);
  k_build<<<gb, 512, 0, stream>>>(x, ws + OFF_E, ws + OFF_WM, ws + OFF_IPR, Mat);

  for (int s = 0; s < 8; ++s) {
    const int k0 = s*64;
    const int mrem = NDIM - k0 - 64;
    k_inv<<<NMAT, 64, 0, stream>>>(Mat, invt, Ld, k0, mrem);
    if (mrem > 0) {
      const int nt = mrem/64;
      dim3 gt(NMAT, nt);
      k_tr1<<<gt, 256, 0, stream>>>(Mat, invt, Lt, k0);
      dim3 gg(NMAT, nt, nt);
      k_gemm<<<gg, 256, 0, stream>>>(Mat, Lt, k0);
    }
  }
  k_final<<<1, 128, 0, stream>>>(ws + OFF_LPR, Ld, out);
}